// Round 1
// baseline (328.206 us; speedup 1.0000x reference)
//
#include <hip/hip_runtime.h>

#define N0 262144
#define N1 16384
#define N2 1024
#define E0 409600
#define E1 20480
#define HD 128
#define OUTD 64

typedef __attribute__((ext_vector_type(8))) __bf16 bf16x8;
typedef __attribute__((ext_vector_type(4))) float f32x4;

__device__ __forceinline__ unsigned short f2bf(float f) {
    unsigned int u = __builtin_bit_cast(unsigned int, f);
    u += 0x7fffu + ((u >> 16) & 1u);
    return (unsigned short)(u >> 16);
}
__device__ __forceinline__ float bf2f(unsigned short h) {
    unsigned int u = ((unsigned int)h) << 16;
    return __builtin_bit_cast(float, u);
}

__global__ __launch_bounds__(256) void pack_b(const float* __restrict__ V,
                                              unsigned short* __restrict__ out, int NT) {
    int tid = blockIdx.x * 256 + threadIdx.x;
    int i  = tid & 7;
    int l  = (tid >> 3) & 63;
    int kt = (tid >> 9) & 31;
    int nt = tid >> 14;
    if (nt >= NT) return;
    int k = kt * 32 + (l >> 4) * 8 + i;
    int j = nt * 16 + (l & 15);
    out[tid] = f2bf(V[(size_t)k * (NT * 16) + j]);
}

__global__ __launch_bounds__(256) void gather_x(const int* __restrict__ src_ids,
                                                const float* __restrict__ emb,
                                                unsigned short* __restrict__ xbf) {
    int w = (blockIdx.x * 256 + threadIdx.x) >> 6;
    int lane = threadIdx.x & 63;
    int nid = src_ids[w];
    float2 v = *(const float2*)(emb + (size_t)nid * HD + lane * 2);
    unsigned int o = (unsigned int)f2bf(v.x) | ((unsigned int)f2bf(v.y) << 16);
    *(unsigned int*)(xbf + (size_t)w * HD + lane * 2) = o;
}

__global__ __launch_bounds__(256) void hist_k(const int* __restrict__ dst, int E,
                                              int* __restrict__ deg) {
    int i = blockIdx.x * 256 + threadIdx.x;
    if (i < E) atomicAdd(&deg[dst[i]], 1);
}

__global__ __launch_bounds__(1024) void scan_k(const int* __restrict__ deg, int n,
                                               int* __restrict__ offs, int* __restrict__ cur) {
    __shared__ int sums[1024];
    int t = threadIdx.x;
    int per = (n + 1023) >> 10;
    int base = t * per;
    int s = 0;
    for (int i = 0; i < per; i++) { int idx = base + i; if (idx < n) s += deg[idx]; }
    sums[t] = s;
    __syncthreads();
    for (int off = 1; off < 1024; off <<= 1) {
        int v = (t >= off) ? sums[t - off] : 0;
        __syncthreads();
        sums[t] += v;
        __syncthreads();
    }
    int run = t ? sums[t - 1] : 0;
    for (int i = 0; i < per; i++) {
        int idx = base + i;
        if (idx < n) { offs[idx] = run; cur[idx] = run; run += deg[idx]; }
    }
    if (t == 1023) offs[n] = sums[1023];
}

__global__ __launch_bounds__(256) void scatter_k(const int* __restrict__ esrc,
                                                 const int* __restrict__ edst,
                                                 const int* __restrict__ etype,
                                                 const float* __restrict__ norm,
                                                 const float* __restrict__ comp,
                                                 int E, int* __restrict__ cur,
                                                 int* __restrict__ ssrc,
                                                 float* __restrict__ scoef) {
    int e = blockIdx.x * 256 + threadIdx.x;
    if (e >= E) return;
    int d = edst[e];
    int pos = atomicAdd(&cur[d], 1);
    ssrc[pos] = esrc[e];
    float nr = norm[e];
    const float4* cp = (const float4*)(comp + (size_t)etype[e] * 8);
    float4 a = cp[0], b = cp[1];
    float4* op = (float4*)(scoef + (size_t)pos * 8);
    op[0] = make_float4(a.x * nr, a.y * nr, a.z * nr, a.w * nr);
    op[1] = make_float4(b.x * nr, b.y * nr, b.z * nr, b.w * nr);
}

__global__ __launch_bounds__(256) void aggregate(const int* __restrict__ offs,
                                                 const int* __restrict__ ssrc,
                                                 const float* __restrict__ scoef,
                                                 const unsigned short* __restrict__ xbf,
                                                 unsigned short* __restrict__ Aout, int Nd) {
    int w = (blockIdx.x * 256 + threadIdx.x) >> 6;
    int lane = threadIdx.x & 63;
    if (w >= Nd) return;
    int beg = offs[w], end = offs[w + 1];
    float acc[16];
#pragma unroll
    for (int i = 0; i < 16; i++) acc[i] = 0.f;
    for (int e = beg; e < end; e++) {
        int src = ssrc[e];
        unsigned int xv = *(const unsigned int*)(xbf + (size_t)src * HD + lane * 2);
        float x0 = bf2f((unsigned short)(xv & 0xffffu));
        float x1 = bf2f((unsigned short)(xv >> 16));
        const float4* cp = (const float4*)(scoef + (size_t)e * 8);
        float4 c0 = cp[0], c1 = cp[1];
        acc[0]  += c0.x * x0; acc[1]  += c0.x * x1;
        acc[2]  += c0.y * x0; acc[3]  += c0.y * x1;
        acc[4]  += c0.z * x0; acc[5]  += c0.z * x1;
        acc[6]  += c0.w * x0; acc[7]  += c0.w * x1;
        acc[8]  += c1.x * x0; acc[9]  += c1.x * x1;
        acc[10] += c1.y * x0; acc[11] += c1.y * x1;
        acc[12] += c1.z * x0; acc[13] += c1.z * x1;
        acc[14] += c1.w * x0; acc[15] += c1.w * x1;
    }
#pragma unroll
    for (int b = 0; b < 8; b++) {
        unsigned int o = (unsigned int)f2bf(acc[2 * b]) | ((unsigned int)f2bf(acc[2 * b + 1]) << 16);
        *(unsigned int*)(Aout + (((size_t)w * 8 + b) * HD) + lane * 2) = o;
    }
}

template <int NT, bool RELU, bool OUTBF>
__global__ __launch_bounds__(256) void gemm_basis(const unsigned short* __restrict__ Abf,
                                                  const unsigned short* __restrict__ Bp,
                                                  const float* __restrict__ bias,
                                                  unsigned short* __restrict__ CoutBf,
                                                  float* __restrict__ CoutF, int M) {
    __shared__ unsigned short aTile[64 * 64];
    const int t = threadIdx.x;
    const int w = t >> 6, lane = t & 63;
    const int row0 = blockIdx.x * 64;
    constexpr int K = 1024;

    f32x4 acc[NT];
#pragma unroll
    for (int i = 0; i < NT; i++) acc[i] = (f32x4){0.f, 0.f, 0.f, 0.f};

    for (int k0 = 0; k0 < K; k0 += 64) {
        __syncthreads();
#pragma unroll
        for (int j = 0; j < 2; j++) {
            int c = t + j * 256;
            int row = c >> 3, col8 = c & 7;
            uint4 v = *(const uint4*)(Abf + (size_t)(row0 + row) * K + k0 + col8 * 8);
            int swc = col8 ^ (row & 7);
            *(uint4*)((char*)aTile + row * 128 + swc * 16) = v;
        }
        __syncthreads();
        int rl = w * 16 + (lane & 15);
#pragma unroll
        for (int kt = 0; kt < 2; kt++) {
            int chunk = kt * 4 + (lane >> 4);
            int swc = chunk ^ (rl & 7);
            bf16x8 af = *(const bf16x8*)((const char*)aTile + rl * 128 + swc * 16);
            int kidx = (k0 >> 5) + kt;
#pragma unroll
            for (int nt = 0; nt < NT; nt++) {
                bf16x8 bfr = *(const bf16x8*)(Bp + (((size_t)nt * 32 + kidx) * 64 + lane) * 8);
                acc[nt] = __builtin_amdgcn_mfma_f32_16x16x32_bf16(af, bfr, acc[nt], 0, 0, 0);
            }
        }
    }
    int colb = lane & 15, rq = lane >> 4;
#pragma unroll
    for (int nt = 0; nt < NT; nt++) {
#pragma unroll
        for (int q = 0; q < 4; q++) {
            int r = row0 + w * 16 + rq * 4 + q;
            int col = nt * 16 + colb;
            float v = acc[nt][q] + bias[col];
            if (RELU) v = v > 0.f ? v : 0.f;
            if (OUTBF) CoutBf[(size_t)r * (NT * 16) + col] = f2bf(v);
            else       CoutF[(size_t)r * (NT * 16) + col] = v;
        }
    }
}

extern "C" void kernel_launch(void* const* d_in, const int* in_sizes, int n_in,
                              void* d_out, int out_size, void* d_ws, size_t ws_size,
                              hipStream_t stream) {
    const int*   src_ids = (const int*)d_in[0];
    const int*   e0_src  = (const int*)d_in[1];
    const int*   e0_dst  = (const int*)d_in[2];
    const int*   e0_type = (const int*)d_in[3];
    const float* norm0   = (const float*)d_in[4];
    const int*   e1_src  = (const int*)d_in[5];
    const int*   e1_dst  = (const int*)d_in[6];
    const int*   e1_type = (const int*)d_in[7];
    const float* norm1   = (const float*)d_in[8];
    const float* emb     = (const float*)d_in[9];
    const float* V1      = (const float*)d_in[10];
    const float* comp1   = (const float*)d_in[11];
    const float* b1      = (const float*)d_in[12];
    const float* V2      = (const float*)d_in[13];
    const float* comp2   = (const float*)d_in[14];
    const float* b2      = (const float*)d_in[15];
    float* out = (float*)d_out;

    char* base = (char*)d_ws;
    size_t off = 0;
    auto alloc = [&](size_t bytes) -> char* {
        off = (off + 255) & ~(size_t)255;
        char* r = base + off;
        off += bytes;
        return r;
    };
    unsigned short* xbf = (unsigned short*)alloc((size_t)N0 * HD * 2);
    unsigned short* A0  = (unsigned short*)alloc((size_t)N1 * 1024 * 2);
    unsigned short* A1  = (unsigned short*)alloc((size_t)N2 * 1024 * 2);
    unsigned short* hbf = (unsigned short*)alloc((size_t)N1 * HD * 2);
    unsigned short* V1p = (unsigned short*)alloc((size_t)1024 * 128 * 2);
    unsigned short* V2p = (unsigned short*)alloc((size_t)1024 * 64 * 2);
    int*   deg0   = (int*)alloc((size_t)N1 * 4);
    int*   offs0  = (int*)alloc((size_t)(N1 + 1) * 4);
    int*   cur0   = (int*)alloc((size_t)N1 * 4);
    int*   deg1   = (int*)alloc((size_t)N2 * 4);
    int*   offs1  = (int*)alloc((size_t)(N2 + 1) * 4);
    int*   cur1   = (int*)alloc((size_t)N2 * 4);
    int*   ssrc0  = (int*)alloc((size_t)E0 * 4);
    float* scoef0 = (float*)alloc((size_t)E0 * 8 * 4);
    int*   ssrc1  = (int*)alloc((size_t)E1 * 4);
    float* scoef1 = (float*)alloc((size_t)E1 * 8 * 4);
    (void)ws_size; (void)in_sizes; (void)n_in; (void)out_size;

    hipMemsetAsync(deg0, 0, (size_t)N1 * 4, stream);
    hipMemsetAsync(deg1, 0, (size_t)N2 * 4, stream);

    pack_b<<<8 * 64, 256, 0, stream>>>(V1, V1p, 8);
    pack_b<<<4 * 64, 256, 0, stream>>>(V2, V2p, 4);
    gather_x<<<N0 / 4, 256, 0, stream>>>(src_ids, emb, xbf);

    hist_k<<<(E0 + 255) / 256, 256, 0, stream>>>(e0_dst, E0, deg0);
    hist_k<<<(E1 + 255) / 256, 256, 0, stream>>>(e1_dst, E1, deg1);
    scan_k<<<1, 1024, 0, stream>>>(deg0, N1, offs0, cur0);
    scan_k<<<1, 1024, 0, stream>>>(deg1, N2, offs1, cur1);
    scatter_k<<<(E0 + 255) / 256, 256, 0, stream>>>(e0_src, e0_dst, e0_type, norm0, comp1,
                                                    E0, cur0, ssrc0, scoef0);
    scatter_k<<<(E1 + 255) / 256, 256, 0, stream>>>(e1_src, e1_dst, e1_type, norm1, comp2,
                                                    E1, cur1, ssrc1, scoef1);

    aggregate<<<N1 / 4, 256, 0, stream>>>(offs0, ssrc0, scoef0, xbf, A0, N1);
    gemm_basis<8, true, true><<<N1 / 64, 256, 0, stream>>>(A0, V1p, b1, hbf, nullptr, N1);
    aggregate<<<N2 / 4, 256, 0, stream>>>(offs1, ssrc1, scoef1, hbf, A1, N2);
    gemm_basis<4, false, false><<<N2 / 64, 256, 0, stream>>>(A1, V2p, b2, nullptr, out, N2);
}

// Round 2
// 229.563 us; speedup vs baseline: 1.4297x; 1.4297x over previous
//
#include <hip/hip_runtime.h>

#define N0 262144
#define N1 16384
#define N2 1024
#define E0 409600
#define E1 20480
#define HD 128

typedef __attribute__((ext_vector_type(8))) __bf16 bf16x8;
typedef __attribute__((ext_vector_type(4))) float f32x4;
typedef __attribute__((ext_vector_type(8))) unsigned short u16x8;

__device__ __forceinline__ unsigned short f2bf(float f) {
    unsigned int u = __builtin_bit_cast(unsigned int, f);
    u += 0x7fffu + ((u >> 16) & 1u);
    return (unsigned short)(u >> 16);
}
__device__ __forceinline__ float bf2f(unsigned short h) {
    unsigned int u = ((unsigned int)h) << 16;
    return __builtin_bit_cast(float, u);
}

// ---- fused setup: gather x, pack V1, pack V2, hist0, hist1 --------------
#define GB   (N0 / 8)          // 32768 gather blocks (8 rows per block, 32 thr/row)
#define PB1  512               // pack V1: 1024*128 elems / 256
#define PB2  256               // pack V2: 1024*64 elems / 256
#define HB0  (E0 / 256)        // 1600
#define HB1  (E1 / 256)        // 80
#define SETUP_BLOCKS (GB + PB1 + PB2 + HB0 + HB1)

__global__ __launch_bounds__(256) void setup_k(const int* __restrict__ src_ids,
                                               const float* __restrict__ emb,
                                               unsigned short* __restrict__ xbf,
                                               const float* __restrict__ V1,
                                               unsigned short* __restrict__ V1p,
                                               const float* __restrict__ V2,
                                               unsigned short* __restrict__ V2p,
                                               const int* __restrict__ e0_dst,
                                               const int* __restrict__ e1_dst,
                                               int* __restrict__ deg0,
                                               int* __restrict__ deg1) {
    int b = blockIdx.x;
    int t = threadIdx.x;
    if (b < GB) {
        // gather: 8 rows per block, 32 threads per row, 4 channels per thread
        int r = b * 8 + (t >> 5);
        int c4 = (t & 31) * 4;
        int nid = src_ids[r];
        float4 v = *(const float4*)(emb + (size_t)nid * HD + c4);
        uint2 o;
        o.x = (unsigned int)f2bf(v.x) | ((unsigned int)f2bf(v.y) << 16);
        o.y = (unsigned int)f2bf(v.z) | ((unsigned int)f2bf(v.w) << 16);
        *(uint2*)(xbf + (size_t)r * HD + c4) = o;
        return;
    }
    b -= GB;
    if (b < PB1 + PB2) {
        // pack V into MFMA-B fragment layout
        const float* V = (b < PB1) ? V1 : V2;
        unsigned short* out = (b < PB1) ? V1p : V2p;
        int NT = (b < PB1) ? 8 : 4;
        int idx = (b < PB1 ? b : b - PB1) * 256 + t;
        int i  = idx & 7;
        int l  = (idx >> 3) & 63;
        int kt = (idx >> 9) & 31;
        int nt = idx >> 14;
        int k = kt * 32 + (l >> 4) * 8 + i;
        int j = nt * 16 + (l & 15);
        out[idx] = f2bf(V[(size_t)k * (NT * 16) + j]);
        return;
    }
    b -= PB1 + PB2;
    if (b < HB0) {
        atomicAdd(&deg0[e0_dst[b * 256 + t]], 1);
        return;
    }
    b -= HB0;
    atomicAdd(&deg1[e1_dst[b * 256 + t]], 1);
}

// ---- single launch, 2 blocks: exclusive scan for both layers ------------
__global__ __launch_bounds__(1024) void scan_k(const int* __restrict__ deg0, int* __restrict__ offs0,
                                               int* __restrict__ cur0,
                                               const int* __restrict__ deg1, int* __restrict__ offs1,
                                               int* __restrict__ cur1) {
    const int* deg = blockIdx.x == 0 ? deg0 : deg1;
    int* offs = blockIdx.x == 0 ? offs0 : offs1;
    int* cur  = blockIdx.x == 0 ? cur0 : cur1;
    int n = blockIdx.x == 0 ? N1 : N2;

    __shared__ int sums[1024];
    int t = threadIdx.x;
    int per = (n + 1023) >> 10;
    int base = t * per;
    int s = 0;
    for (int i = 0; i < per; i++) { int idx = base + i; if (idx < n) s += deg[idx]; }
    sums[t] = s;
    __syncthreads();
    for (int off = 1; off < 1024; off <<= 1) {
        int v = (t >= off) ? sums[t - off] : 0;
        __syncthreads();
        sums[t] += v;
        __syncthreads();
    }
    int run = t ? sums[t - 1] : 0;
    for (int i = 0; i < per; i++) {
        int idx = base + i;
        if (idx < n) { offs[idx] = run; cur[idx] = run; run += deg[idx]; }
    }
    if (t == 1023) offs[n] = sums[1023];
}

// ---- merged scatter: dst-sort edges, coef = bf16(norm*comp[r]) ----------
__global__ __launch_bounds__(256) void scatter_k(const int* __restrict__ e0s, const int* __restrict__ e0d,
                                                 const int* __restrict__ e0t, const float* __restrict__ n0,
                                                 const float* __restrict__ c1,
                                                 int* __restrict__ cur0, int* __restrict__ ssrc0,
                                                 u16x8* __restrict__ coef0,
                                                 const int* __restrict__ e1s, const int* __restrict__ e1d,
                                                 const int* __restrict__ e1t, const float* __restrict__ n1,
                                                 const float* __restrict__ c2,
                                                 int* __restrict__ cur1, int* __restrict__ ssrc1,
                                                 u16x8* __restrict__ coef1) {
    int b = blockIdx.x;
    const int *esrc, *edst, *etype; const float *norm, *comp;
    int *cur, *ssrc; u16x8* coef; int e;
    if (b < HB0) {
        esrc = e0s; edst = e0d; etype = e0t; norm = n0; comp = c1;
        cur = cur0; ssrc = ssrc0; coef = coef0; e = b * 256 + threadIdx.x;
    } else {
        esrc = e1s; edst = e1d; etype = e1t; norm = n1; comp = c2;
        cur = cur1; ssrc = ssrc1; coef = coef1; e = (b - HB0) * 256 + threadIdx.x;
    }
    int d = edst[e];
    int pos = atomicAdd(&cur[d], 1);
    ssrc[pos] = esrc[e];
    float nr = norm[e];
    const float4* cp = (const float4*)(comp + (size_t)etype[e] * 8);
    float4 a = cp[0], bb = cp[1];
    u16x8 cw;
    cw[0] = f2bf(a.x * nr);  cw[1] = f2bf(a.y * nr);
    cw[2] = f2bf(a.z * nr);  cw[3] = f2bf(a.w * nr);
    cw[4] = f2bf(bb.x * nr); cw[5] = f2bf(bb.y * nr);
    cw[6] = f2bf(bb.z * nr); cw[7] = f2bf(bb.w * nr);
    coef[pos] = cw;
}

// ---- aggregate: A[v][b][ch] = sum coef[e][b]*x[src_e][ch], sw-pipelined --
__global__ __launch_bounds__(256) void aggregate(const int* __restrict__ offs,
                                                 const int* __restrict__ ssrc,
                                                 const u16x8* __restrict__ coef,
                                                 const unsigned short* __restrict__ xbf,
                                                 unsigned short* __restrict__ Aout, int Nd) {
    int w = (blockIdx.x * 256 + threadIdx.x) >> 6;
    int lane = threadIdx.x & 63;
    if (w >= Nd) return;
    int beg = offs[w], end = offs[w + 1];
    float acc[16];
#pragma unroll
    for (int i = 0; i < 16; i++) acc[i] = 0.f;
    if (beg < end) {
        int last = end - 1;
        int e1 = beg + 1 > last ? last : beg + 1;
        int srcA = ssrc[beg];
        int srcB = ssrc[e1];
        u16x8 cA = coef[beg];
        unsigned int xvA = *(const unsigned int*)(xbf + (size_t)srcA * HD + lane * 2);
        for (int e = beg; e < end; e++) {
            int en1 = e + 1 > last ? last : e + 1;
            int en2 = e + 2 > last ? last : e + 2;
            int srcC = ssrc[en2];                      // prefetch distance 2
            u16x8 cB = coef[en1];                      // prefetch distance 1
            unsigned int xvB = *(const unsigned int*)(xbf + (size_t)srcB * HD + lane * 2); // dist 1
            float x0 = bf2f((unsigned short)(xvA & 0xffffu));
            float x1 = bf2f((unsigned short)(xvA >> 16));
#pragma unroll
            for (int bb = 0; bb < 8; bb++) {
                float cb = bf2f(cA[bb]);
                acc[2 * bb]     += cb * x0;
                acc[2 * bb + 1] += cb * x1;
            }
            srcA = srcB; srcB = srcC; cA = cB; xvA = xvB;
        }
    }
#pragma unroll
    for (int bb = 0; bb < 8; bb++) {
        unsigned int o = (unsigned int)f2bf(acc[2 * bb]) | ((unsigned int)f2bf(acc[2 * bb + 1]) << 16);
        *(unsigned int*)(Aout + (((size_t)w * 8 + bb) * HD) + lane * 2) = o;
    }
}

// ---- GEMM: C[M, NT*16] = A[M,1024]bf16 @ Bpacked (+bias, opt ReLU) -------
// 64-row tile, K_STEP=128; wave w: rows (w&1)*32..+31 (two 16-row frags),
// cols (w>>1)*(NT/2)*16 .. ; LDS 16KB, 16B-chunk XOR swizzle.
template <int NT, bool RELU, bool OUTBF>
__global__ __launch_bounds__(256) void gemm_basis(const unsigned short* __restrict__ Abf,
                                                  const unsigned short* __restrict__ Bp,
                                                  const float* __restrict__ bias,
                                                  unsigned short* __restrict__ CoutBf,
                                                  float* __restrict__ CoutF) {
    __shared__ unsigned short aTile[64 * 128];   // 16 KB
    const int t = threadIdx.x;
    const int w = t >> 6, lane = t & 63;
    const int row0 = blockIdx.x * 64;
    constexpr int K = 1024;
    constexpr int NH = NT / 2;
    const int h = w & 1;
    const int ntBase = (w >> 1) * NH;
    const int rl0 = h * 32 + (lane & 15);
    const int rl1 = rl0 + 16;
    const int swz = rl0 & 15;

    f32x4 acc0[NH], acc1[NH];
#pragma unroll
    for (int i = 0; i < NH; i++) {
        acc0[i] = (f32x4){0.f, 0.f, 0.f, 0.f};
        acc1[i] = (f32x4){0.f, 0.f, 0.f, 0.f};
    }

    for (int k0 = 0; k0 < K; k0 += 128) {
        __syncthreads();
#pragma unroll
        for (int j = 0; j < 4; j++) {
            int c = t + j * 256;                 // 16B-chunk id 0..1023
            int row = c >> 4, col = c & 15;
            uint4 v = *(const uint4*)(Abf + (size_t)(row0 + row) * K + k0 + col * 8);
            int swc = col ^ (row & 15);
            *(uint4*)((char*)aTile + row * 256 + swc * 16) = v;
        }
        __syncthreads();
#pragma unroll
        for (int kt = 0; kt < 4; kt++) {
            int chunk = kt * 4 + (lane >> 4);
            bf16x8 a0 = *(const bf16x8*)((const char*)aTile + rl0 * 256 + (chunk ^ swz) * 16);
            bf16x8 a1 = *(const bf16x8*)((const char*)aTile + rl1 * 256 + (chunk ^ swz) * 16);
            int kidx = (k0 >> 5) + kt;
#pragma unroll
            for (int nt = 0; nt < NH; nt++) {
                bf16x8 bfr = *(const bf16x8*)(Bp + (((size_t)(ntBase + nt) * 32 + kidx) * 64 + lane) * 8);
                acc0[nt] = __builtin_amdgcn_mfma_f32_16x16x32_bf16(a0, bfr, acc0[nt], 0, 0, 0);
                acc1[nt] = __builtin_amdgcn_mfma_f32_16x16x32_bf16(a1, bfr, acc1[nt], 0, 0, 0);
            }
        }
    }
    int colb = lane & 15, rq = lane >> 4;
#pragma unroll
    for (int nt = 0; nt < NH; nt++) {
        int col = (ntBase + nt) * 16 + colb;
        float bv = bias[col];
#pragma unroll
        for (int q = 0; q < 4; q++) {
            int r = row0 + h * 32 + rq * 4 + q;
            float v0 = acc0[nt][q] + bv;
            float v1 = acc1[nt][q] + bv;
            if (RELU) { v0 = v0 > 0.f ? v0 : 0.f; v1 = v1 > 0.f ? v1 : 0.f; }
            if (OUTBF) {
                CoutBf[(size_t)r * (NT * 16) + col] = f2bf(v0);
                CoutBf[(size_t)(r + 16) * (NT * 16) + col] = f2bf(v1);
            } else {
                CoutF[(size_t)r * (NT * 16) + col] = v0;
                CoutF[(size_t)(r + 16) * (NT * 16) + col] = v1;
            }
        }
    }
}

extern "C" void kernel_launch(void* const* d_in, const int* in_sizes, int n_in,
                              void* d_out, int out_size, void* d_ws, size_t ws_size,
                              hipStream_t stream) {
    const int*   src_ids = (const int*)d_in[0];
    const int*   e0_src  = (const int*)d_in[1];
    const int*   e0_dst  = (const int*)d_in[2];
    const int*   e0_type = (const int*)d_in[3];
    const float* norm0   = (const float*)d_in[4];
    const int*   e1_src  = (const int*)d_in[5];
    const int*   e1_dst  = (const int*)d_in[6];
    const int*   e1_type = (const int*)d_in[7];
    const float* norm1   = (const float*)d_in[8];
    const float* emb     = (const float*)d_in[9];
    const float* V1      = (const float*)d_in[10];
    const float* comp1   = (const float*)d_in[11];
    const float* b1      = (const float*)d_in[12];
    const float* V2      = (const float*)d_in[13];
    const float* comp2   = (const float*)d_in[14];
    const float* b2      = (const float*)d_in[15];
    float* out = (float*)d_out;

    char* base = (char*)d_ws;
    size_t off = 0;
    auto alloc = [&](size_t bytes) -> char* {
        off = (off + 255) & ~(size_t)255;
        char* r = base + off;
        off += bytes;
        return r;
    };
    unsigned short* xbf = (unsigned short*)alloc((size_t)N0 * HD * 2);
    unsigned short* A0  = (unsigned short*)alloc((size_t)N1 * 1024 * 2);
    unsigned short* A1  = (unsigned short*)alloc((size_t)N2 * 1024 * 2);
    unsigned short* hbf = (unsigned short*)alloc((size_t)N1 * HD * 2);
    unsigned short* V1p = (unsigned short*)alloc((size_t)1024 * 128 * 2);
    unsigned short* V2p = (unsigned short*)alloc((size_t)1024 * 64 * 2);
    int*   deg    = (int*)alloc((size_t)(N1 + N2) * 4);     // deg0 | deg1 adjacent
    int*   deg0   = deg;
    int*   deg1   = deg + N1;
    int*   offs0  = (int*)alloc((size_t)(N1 + 1) * 4);
    int*   cur0   = (int*)alloc((size_t)N1 * 4);
    int*   offs1  = (int*)alloc((size_t)(N2 + 1) * 4);
    int*   cur1   = (int*)alloc((size_t)N2 * 4);
    int*   ssrc0  = (int*)alloc((size_t)E0 * 4);
    u16x8* coef0  = (u16x8*)alloc((size_t)E0 * 16);
    int*   ssrc1  = (int*)alloc((size_t)E1 * 4);
    u16x8* coef1  = (u16x8*)alloc((size_t)E1 * 16);
    (void)ws_size; (void)in_sizes; (void)n_in; (void)out_size;

    hipMemsetAsync(deg, 0, (size_t)(N1 + N2) * 4, stream);

    setup_k<<<SETUP_BLOCKS, 256, 0, stream>>>(src_ids, emb, xbf, V1, V1p, V2, V2p,
                                              e0_dst, e1_dst, deg0, deg1);
    scan_k<<<2, 1024, 0, stream>>>(deg0, offs0, cur0, deg1, offs1, cur1);
    scatter_k<<<HB0 + HB1, 256, 0, stream>>>(e0_src, e0_dst, e0_type, norm0, comp1,
                                             cur0, ssrc0, coef0,
                                             e1_src, e1_dst, e1_type, norm1, comp2,
                                             cur1, ssrc1, coef1);
    aggregate<<<N1 / 4, 256, 0, stream>>>(offs0, ssrc0, coef0, xbf, A0, N1);
    gemm_basis<8, true, true><<<N1 / 64, 256, 0, stream>>>(A0, V1p, b1, hbf, nullptr);
    aggregate<<<N2 / 4, 256, 0, stream>>>(offs1, ssrc1, coef1, hbf, A1, N2);
    gemm_basis<4, false, false><<<N2 / 64, 256, 0, stream>>>(A1, V2p, b2, nullptr, out);
}

// Round 4
// 185.275 us; speedup vs baseline: 1.7715x; 1.2390x over previous
//
#include <hip/hip_runtime.h>

#define N0 262144
#define N1 16384
#define N2 1024
#define E0 409600
#define E1 20480
#define HD 128
#define PACK1 131072   // 1024*128
#define PACK2 65536    // 1024*64

typedef __attribute__((ext_vector_type(8))) __bf16 bf16x8;
typedef __attribute__((ext_vector_type(4))) float f32x4;

__device__ __forceinline__ unsigned short f2bf(float f) {
    unsigned int u = __builtin_bit_cast(unsigned int, f);
    u += 0x7fffu + ((u >> 16) & 1u);
    return (unsigned short)(u >> 16);
}
__device__ __forceinline__ float bf2f(unsigned short h) {
    unsigned int u = ((unsigned int)h) << 16;
    return __builtin_bit_cast(float, u);
}

// ---- fused setup: pack V1, pack V2, hist0, hist1 (grid-stride) ----------
__global__ __launch_bounds__(256) void setup_k(const float* __restrict__ V1,
                                               unsigned short* __restrict__ V1p,
                                               const float* __restrict__ V2,
                                               unsigned short* __restrict__ V2p,
                                               const int* __restrict__ e0_dst,
                                               const int* __restrict__ e1_dst,
                                               int* __restrict__ deg0,
                                               int* __restrict__ deg1) {
    int stride = gridDim.x * 256;
    const int total = PACK1 + PACK2 + E0 + E1;
    for (int idx = blockIdx.x * 256 + threadIdx.x; idx < total; idx += stride) {
        if (idx < PACK1 + PACK2) {
            const float* V = idx < PACK1 ? V1 : V2;
            unsigned short* o = idx < PACK1 ? V1p : V2p;
            int NT = idx < PACK1 ? 8 : 4;
            int q = idx < PACK1 ? idx : idx - PACK1;
            int i  = q & 7;
            int l  = (q >> 3) & 63;
            int kt = (q >> 9) & 31;
            int nt = q >> 14;
            int k = kt * 32 + (l >> 4) * 8 + i;
            int j = nt * 16 + (l & 15);
            o[q] = f2bf(V[(size_t)k * (NT * 16) + j]);
        } else if (idx < PACK1 + PACK2 + E0) {
            atomicAdd(&deg0[e0_dst[idx - (PACK1 + PACK2)]], 1);
        } else {
            atomicAdd(&deg1[e1_dst[idx - (PACK1 + PACK2 + E0)]], 1);
        }
    }
}

// ---- 2 blocks: exclusive scan for both layers ---------------------------
__global__ __launch_bounds__(1024) void scan_k(const int* __restrict__ deg0, int* __restrict__ offs0,
                                               int* __restrict__ cur0,
                                               const int* __restrict__ deg1, int* __restrict__ offs1,
                                               int* __restrict__ cur1) {
    const int* deg = blockIdx.x == 0 ? deg0 : deg1;
    int* offs = blockIdx.x == 0 ? offs0 : offs1;
    int* cur  = blockIdx.x == 0 ? cur0 : cur1;
    int n = blockIdx.x == 0 ? N1 : N2;

    __shared__ int sums[1024];
    int t = threadIdx.x;
    int per = (n + 1023) >> 10;
    int base = t * per;
    int s = 0;
    for (int i = 0; i < per; i++) { int idx = base + i; if (idx < n) s += deg[idx]; }
    sums[t] = s;
    __syncthreads();
    for (int off = 1; off < 1024; off <<= 1) {
        int v = (t >= off) ? sums[t - off] : 0;
        __syncthreads();
        sums[t] += v;
        __syncthreads();
    }
    int run = t ? sums[t - 1] : 0;
    for (int i = 0; i < per; i++) {
        int idx = base + i;
        if (idx < n) { offs[idx] = run; cur[idx] = run; run += deg[idx]; }
    }
    if (t == 1023) offs[n] = sums[1023];
}

// ---- scatter: dst-sort edges; layer0 translates src -> emb row id --------
__global__ __launch_bounds__(256) void scatter_k(const int* __restrict__ src_ids,
                                                 const int* __restrict__ e0s, const int* __restrict__ e0d,
                                                 const int* __restrict__ e0t, const float* __restrict__ n0,
                                                 const float* __restrict__ c1,
                                                 int* __restrict__ cur0, int* __restrict__ ssrc0,
                                                 float* __restrict__ coef0,
                                                 const int* __restrict__ e1s, const int* __restrict__ e1d,
                                                 const int* __restrict__ e1t, const float* __restrict__ n1,
                                                 const float* __restrict__ c2,
                                                 int* __restrict__ cur1, int* __restrict__ ssrc1,
                                                 float* __restrict__ coef1) {
    int stride = gridDim.x * 256;
    for (int i = blockIdx.x * 256 + threadIdx.x; i < E0 + E1; i += stride) {
        if (i < E0) {
            int e = i;
            int pos = atomicAdd(&cur0[e0d[e]], 1);
            ssrc0[pos] = src_ids[e0s[e]];       // direct emb row id
            float nr = n0[e];
            const float4* cp = (const float4*)(c1 + (size_t)e0t[e] * 8);
            float4 a = cp[0], b = cp[1];
            float4* op = (float4*)(coef0 + (size_t)pos * 8);
            op[0] = make_float4(a.x * nr, a.y * nr, a.z * nr, a.w * nr);
            op[1] = make_float4(b.x * nr, b.y * nr, b.z * nr, b.w * nr);
        } else {
            int e = i - E0;
            int pos = atomicAdd(&cur1[e1d[e]], 1);
            ssrc1[pos] = e1s[e];
            float nr = n1[e];
            const float4* cp = (const float4*)(c2 + (size_t)e1t[e] * 8);
            float4 a = cp[0], b = cp[1];
            float4* op = (float4*)(coef1 + (size_t)pos * 8);
            op[0] = make_float4(a.x * nr, a.y * nr, a.z * nr, a.w * nr);
            op[1] = make_float4(b.x * nr, b.y * nr, b.z * nr, b.w * nr);
        }
    }
}

// ---- aggregate: A[v][b][ch] = sum coef[e][b]*x[src_e][ch] ----------------
// L0: x = fp32 emb rows (ids pre-translated). else: x = bf16 h rows.
template <bool L0>
__global__ __launch_bounds__(256) void aggregate(const int* __restrict__ offs,
                                                 const int* __restrict__ ssrc,
                                                 const float* __restrict__ coef,
                                                 const float* __restrict__ xf,
                                                 const unsigned short* __restrict__ xh,
                                                 unsigned short* __restrict__ Aout, int Nd) {
    int gw = (blockIdx.x * 256 + threadIdx.x) >> 6;
    int nw = gridDim.x * 4;
    int lane = threadIdx.x & 63;
    for (int w = gw; w < Nd; w += nw) {
        int beg = offs[w], end = offs[w + 1];
        float acc[16];
#pragma unroll
        for (int i = 0; i < 16; i++) acc[i] = 0.f;
        if (beg < end) {
            int last = end - 1;
            auto ldx = [&](int s) -> float2 {
                if constexpr (L0) {
                    return *(const float2*)(xf + (size_t)s * HD + lane * 2);
                } else {
                    unsigned int u = *(const unsigned int*)(xh + (size_t)s * HD + lane * 2);
                    return make_float2(bf2f((unsigned short)(u & 0xffffu)),
                                       bf2f((unsigned short)(u >> 16)));
                }
            };
            int s1 = ssrc[beg];
            int s2 = (beg + 1 <= last) ? ssrc[beg + 1] : s1;
            int s3 = (beg + 2 <= last) ? ssrc[beg + 2] : s2;
            float2 x0 = ldx(s1);
            float2 x1 = ldx(s2);
            float4 c0a = *(const float4*)(coef + (size_t)beg * 8);
            float4 c0b = *(const float4*)(coef + (size_t)beg * 8 + 4);
            for (int e = beg; e <= last; e++) {
                int e3 = (e + 3 <= last) ? e + 3 : last;
                int e1 = (e + 1 <= last) ? e + 1 : last;
                int s4 = ssrc[e3];               // id prefetch dist 3
                float2 x2 = ldx(s3);             // x prefetch dist 2
                float4 c1a = *(const float4*)(coef + (size_t)e1 * 8);
                float4 c1b = *(const float4*)(coef + (size_t)e1 * 8 + 4);
                acc[0]  += c0a.x * x0.x; acc[1]  += c0a.x * x0.y;
                acc[2]  += c0a.y * x0.x; acc[3]  += c0a.y * x0.y;
                acc[4]  += c0a.z * x0.x; acc[5]  += c0a.z * x0.y;
                acc[6]  += c0a.w * x0.x; acc[7]  += c0a.w * x0.y;
                acc[8]  += c0b.x * x0.x; acc[9]  += c0b.x * x0.y;
                acc[10] += c0b.y * x0.x; acc[11] += c0b.y * x0.y;
                acc[12] += c0b.z * x0.x; acc[13] += c0b.z * x0.y;
                acc[14] += c0b.w * x0.x; acc[15] += c0b.w * x0.y;
                x0 = x1; x1 = x2; s3 = s4;
                c0a = c1a; c0b = c1b;
            }
        }
#pragma unroll
        for (int bb = 0; bb < 8; bb++) {
            unsigned int o = (unsigned int)f2bf(acc[2 * bb]) | ((unsigned int)f2bf(acc[2 * bb + 1]) << 16);
            *(unsigned int*)(Aout + (((size_t)w * 8 + bb) * HD) + lane * 2) = o;
        }
    }
}

// ---- GEMM: C[M, NT*16] = A[M,1024]bf16 @ Bpacked (+bias, opt ReLU) -------
// 512 threads = 8 waves per block, 64-row tile, K_STEP=128.
// NT=8: wave w -> nt=w, 4 row-frags (rows 0..63).
// NT=4: wave w -> nt=w>>1, 2 row-frags at (w&1)*32.
template <int NT, bool RELU, bool OUTBF>
__global__ __launch_bounds__(512) void gemm_basis(const unsigned short* __restrict__ Abf,
                                                  const unsigned short* __restrict__ Bp,
                                                  const float* __restrict__ bias,
                                                  unsigned short* __restrict__ CoutBf,
                                                  float* __restrict__ CoutF) {
    __shared__ unsigned short aTile[64 * 128];   // 16 KB
    const int t = threadIdx.x;                   // 0..511
    const int w = t >> 6, lane = t & 63;         // w 0..7
    const int row0 = blockIdx.x * 64;
    constexpr int FR = (NT == 8) ? 4 : 2;
    const int ntIdx = (NT == 8) ? w : (w >> 1);
    const int fr0 = (NT == 8) ? 0 : (w & 1) * 32;

    f32x4 acc[FR];
#pragma unroll
    for (int f = 0; f < FR; f++) acc[f] = (f32x4){0.f, 0.f, 0.f, 0.f};

    for (int k0 = 0; k0 < 1024; k0 += 128) {
        __syncthreads();
#pragma unroll
        for (int j = 0; j < 2; j++) {
            int c = t + j * 512;                 // 16B-chunk id 0..1023
            int row = c >> 4, col = c & 15;
            uint4 v = *(const uint4*)(Abf + (size_t)(row0 + row) * 1024 + k0 + col * 8);
            *(uint4*)((char*)aTile + row * 256 + (col ^ (row & 15)) * 16) = v;
        }
        __syncthreads();
#pragma unroll
        for (int kt = 0; kt < 4; kt++) {
            int chunk = kt * 4 + (lane >> 4);
            int kidx = (k0 >> 5) + kt;
            bf16x8 bfr = *(const bf16x8*)(Bp + (((size_t)ntIdx * 32 + kidx) * 64 + lane) * 8);
#pragma unroll
            for (int f = 0; f < FR; f++) {
                int rl = fr0 + f * 16 + (lane & 15);
                bf16x8 af = *(const bf16x8*)((const char*)aTile + rl * 256 + ((chunk ^ (rl & 15)) * 16));
                acc[f] = __builtin_amdgcn_mfma_f32_16x16x32_bf16(af, bfr, acc[f], 0, 0, 0);
            }
        }
    }
    int colb = lane & 15, rq = lane >> 4;
    int col = ntIdx * 16 + colb;
    float bv = bias[col];
#pragma unroll
    for (int f = 0; f < FR; f++) {
#pragma unroll
        for (int q = 0; q < 4; q++) {
            int r = row0 + fr0 + f * 16 + rq * 4 + q;
            float v = acc[f][q] + bv;
            if (RELU) v = v > 0.f ? v : 0.f;
            if (OUTBF) CoutBf[(size_t)r * (NT * 16) + col] = f2bf(v);
            else       CoutF[(size_t)r * (NT * 16) + col] = v;
        }
    }
}

extern "C" void kernel_launch(void* const* d_in, const int* in_sizes, int n_in,
                              void* d_out, int out_size, void* d_ws, size_t ws_size,
                              hipStream_t stream) {
    const int*   src_ids = (const int*)d_in[0];
    const int*   e0_src  = (const int*)d_in[1];
    const int*   e0_dst  = (const int*)d_in[2];
    const int*   e0_type = (const int*)d_in[3];
    const float* norm0   = (const float*)d_in[4];
    const int*   e1_src  = (const int*)d_in[5];
    const int*   e1_dst  = (const int*)d_in[6];
    const int*   e1_type = (const int*)d_in[7];
    const float* norm1   = (const float*)d_in[8];
    const float* emb     = (const float*)d_in[9];
    const float* V1      = (const float*)d_in[10];
    const float* comp1   = (const float*)d_in[11];
    const float* b1      = (const float*)d_in[12];
    const float* V2      = (const float*)d_in[13];
    const float* comp2   = (const float*)d_in[14];
    const float* b2      = (const float*)d_in[15];
    float* out = (float*)d_out;

    char* base = (char*)d_ws;
    size_t off = 0;
    auto alloc = [&](size_t bytes) -> char* {
        off = (off + 255) & ~(size_t)255;
        char* r = base + off;
        off += bytes;
        return r;
    };
    unsigned short* A0  = (unsigned short*)alloc((size_t)N1 * 1024 * 2);
    unsigned short* A1  = (unsigned short*)alloc((size_t)N2 * 1024 * 2);
    unsigned short* hbf = (unsigned short*)alloc((size_t)N1 * HD * 2);
    unsigned short* V1p = (unsigned short*)alloc((size_t)1024 * 128 * 2);
    unsigned short* V2p = (unsigned short*)alloc((size_t)1024 * 64 * 2);
    int*   deg    = (int*)alloc((size_t)(N1 + N2) * 4);
    int*   deg0   = deg;
    int*   deg1   = deg + N1;
    int*   offs0  = (int*)alloc((size_t)(N1 + 1) * 4);
    int*   cur0   = (int*)alloc((size_t)N1 * 4);
    int*   offs1  = (int*)alloc((size_t)(N2 + 1) * 4);
    int*   cur1   = (int*)alloc((size_t)N2 * 4);
    int*   ssrc0  = (int*)alloc((size_t)E0 * 4);
    float* coef0  = (float*)alloc((size_t)E0 * 32);
    int*   ssrc1  = (int*)alloc((size_t)E1 * 4);
    float* coef1  = (float*)alloc((size_t)E1 * 32);
    (void)ws_size; (void)in_sizes; (void)n_in; (void)out_size;

    hipMemsetAsync(deg, 0, (size_t)(N1 + N2) * 4, stream);

    setup_k<<<512, 256, 0, stream>>>(V1, V1p, V2, V2p, e0_dst, e1_dst, deg0, deg1);
    scan_k<<<2, 1024, 0, stream>>>(deg0, offs0, cur0, deg1, offs1, cur1);
    scatter_k<<<512, 256, 0, stream>>>(src_ids, e0_src, e0_dst, e0_type, norm0, comp1,
                                       cur0, ssrc0, coef0,
                                       e1_src, e1_dst, e1_type, norm1, comp2,
                                       cur1, ssrc1, coef1);
    aggregate<true><<<2048, 256, 0, stream>>>(offs0, ssrc0, coef0, emb, nullptr, A0, N1);
    gemm_basis<8, true, true><<<N1 / 64, 512, 0, stream>>>(A0, V1p, b1, hbf, nullptr);
    aggregate<false><<<256, 256, 0, stream>>>(offs1, ssrc1, coef1, nullptr, hbf, A1, N2);
    gemm_basis<4, false, false><<<N2 / 64, 512, 0, stream>>>(A1, V2p, b2, nullptr, out);
}

// Round 5
// 181.953 us; speedup vs baseline: 1.8038x; 1.0183x over previous
//
#include <hip/hip_runtime.h>

#define N0 262144
#define N1 16384
#define N2 1024
#define E0 409600
#define E1 20480
#define HD 128
#define PACK1 131072   // 1024*128
#define PACK2 65536    // 1024*64

typedef __attribute__((ext_vector_type(8))) __bf16 bf16x8;
typedef __attribute__((ext_vector_type(4))) float f32x4;

__device__ __forceinline__ unsigned short f2bf(float f) {
    unsigned int u = __builtin_bit_cast(unsigned int, f);
    u += 0x7fffu + ((u >> 16) & 1u);
    return (unsigned short)(u >> 16);
}
__device__ __forceinline__ float bf2f(unsigned short h) {
    unsigned int u = ((unsigned int)h) << 16;
    return __builtin_bit_cast(float, u);
}

// ---- fused setup: pack V1, pack V2, hist0, hist1 (grid-stride) ----------
__global__ __launch_bounds__(256) void setup_k(const float* __restrict__ V1,
                                               unsigned short* __restrict__ V1p,
                                               const float* __restrict__ V2,
                                               unsigned short* __restrict__ V2p,
                                               const int* __restrict__ e0_dst,
                                               const int* __restrict__ e1_dst,
                                               int* __restrict__ deg0,
                                               int* __restrict__ deg1) {
    int stride = gridDim.x * 256;
    const int total = PACK1 + PACK2 + E0 + E1;
    for (int idx = blockIdx.x * 256 + threadIdx.x; idx < total; idx += stride) {
        if (idx < PACK1 + PACK2) {
            const float* V = idx < PACK1 ? V1 : V2;
            unsigned short* o = idx < PACK1 ? V1p : V2p;
            int NT = idx < PACK1 ? 8 : 4;
            int q = idx < PACK1 ? idx : idx - PACK1;
            int i  = q & 7;
            int l  = (q >> 3) & 63;
            int kt = (q >> 9) & 31;
            int nt = q >> 14;
            int k = kt * 32 + (l >> 4) * 8 + i;
            int j = nt * 16 + (l & 15);
            o[q] = f2bf(V[(size_t)k * (NT * 16) + j]);
        } else if (idx < PACK1 + PACK2 + E0) {
            atomicAdd(&deg0[e0_dst[idx - (PACK1 + PACK2)]], 1);
        } else {
            atomicAdd(&deg1[e1_dst[idx - (PACK1 + PACK2 + E0)]], 1);
        }
    }
}

// ---- 2 blocks: exclusive scan for both layers ---------------------------
__global__ __launch_bounds__(1024) void scan_k(const int* __restrict__ deg0, int* __restrict__ offs0,
                                               int* __restrict__ cur0,
                                               const int* __restrict__ deg1, int* __restrict__ offs1,
                                               int* __restrict__ cur1) {
    const int* deg = blockIdx.x == 0 ? deg0 : deg1;
    int* offs = blockIdx.x == 0 ? offs0 : offs1;
    int* cur  = blockIdx.x == 0 ? cur0 : cur1;
    int n = blockIdx.x == 0 ? N1 : N2;

    __shared__ int sums[1024];
    int t = threadIdx.x;
    int per = (n + 1023) >> 10;
    int base = t * per;
    int s = 0;
    for (int i = 0; i < per; i++) { int idx = base + i; if (idx < n) s += deg[idx]; }
    sums[t] = s;
    __syncthreads();
    for (int off = 1; off < 1024; off <<= 1) {
        int v = (t >= off) ? sums[t - off] : 0;
        __syncthreads();
        sums[t] += v;
        __syncthreads();
    }
    int run = t ? sums[t - 1] : 0;
    for (int i = 0; i < per; i++) {
        int idx = base + i;
        if (idx < n) { offs[idx] = run; cur[idx] = run; run += deg[idx]; }
    }
    if (t == 1023) offs[n] = sums[1023];
}

// ---- scatter: dst-sort edges into 8B records {src|type<<24, norm} --------
__global__ __launch_bounds__(256) void scatter_k(const int* __restrict__ src_ids,
                                                 const int* __restrict__ e0s, const int* __restrict__ e0d,
                                                 const int* __restrict__ e0t, const float* __restrict__ n0,
                                                 int* __restrict__ cur0, int2* __restrict__ rec0,
                                                 const int* __restrict__ e1s, const int* __restrict__ e1d,
                                                 const int* __restrict__ e1t, const float* __restrict__ n1,
                                                 int* __restrict__ cur1, int2* __restrict__ rec1) {
    int stride = gridDim.x * 256;
    for (int i = blockIdx.x * 256 + threadIdx.x; i < E0 + E1; i += stride) {
        if (i < E0) {
            int e = i;
            int pos = atomicAdd(&cur0[e0d[e]], 1);
            rec0[pos] = make_int2(src_ids[e0s[e]] | (e0t[e] << 24),
                                  __builtin_bit_cast(int, n0[e]));
        } else {
            int e = i - E0;
            int pos = atomicAdd(&cur1[e1d[e]], 1);
            rec1[pos] = make_int2(e1s[e] | (e1t[e] << 24),
                                  __builtin_bit_cast(int, n1[e]));
        }
    }
}

// ---- per-row aggregation into registers (software-pipelined) -------------
// acc[2b] / acc[2b+1] = sum_e comp[type_e][b] * norm_e * x[src_e][lane*2(+1)]
template <bool L0>
__device__ __forceinline__ void agg_row(const int* __restrict__ offs,
                                        const int2* __restrict__ rec,
                                        const float* __restrict__ comp,
                                        const float* __restrict__ xf,
                                        const unsigned short* __restrict__ xh,
                                        int dst, int lane, float* acc) {
#pragma unroll
    for (int i = 0; i < 16; i++) acc[i] = 0.f;
    int beg = offs[dst], end = offs[dst + 1];
    if (beg >= end) return;
    int last = end - 1;
    auto ldx = [&](int s) -> float2 {
        if constexpr (L0) {
            return *(const float2*)(xf + (size_t)s * HD + lane * 2);
        } else {
            unsigned int u = *(const unsigned int*)(xh + (size_t)s * HD + lane * 2);
            return make_float2(bf2f((unsigned short)(u & 0xffffu)),
                               bf2f((unsigned short)(u >> 16)));
        }
    };
    int2 rA = rec[beg];
    int2 rB = rec[beg + 1 <= last ? beg + 1 : last];
    int2 rC = rec[beg + 2 <= last ? beg + 2 : last];
    float2 x0 = ldx(rA.x & 0xFFFFFF);
    float2 x1 = ldx(rB.x & 0xFFFFFF);
    const float4* cpA = (const float4*)(comp + (size_t)((unsigned)rA.x >> 24) * 8);
    float4 cA0 = cpA[0], cA1 = cpA[1];
    for (int e = beg; e <= last; e++) {
        int2 rD = rec[e + 3 <= last ? e + 3 : last];       // rec prefetch dist 3
        float2 x2 = ldx(rC.x & 0xFFFFFF);                  // x prefetch dist 2
        const float4* cpB = (const float4*)(comp + (size_t)((unsigned)rB.x >> 24) * 8);
        float4 cB0 = cpB[0], cB1 = cpB[1];                 // comp prefetch dist 1
        float nrm = __builtin_bit_cast(float, rA.y);
        float xx = x0.x * nrm, xy = x0.y * nrm;
        acc[0]  += cA0.x * xx; acc[1]  += cA0.x * xy;
        acc[2]  += cA0.y * xx; acc[3]  += cA0.y * xy;
        acc[4]  += cA0.z * xx; acc[5]  += cA0.z * xy;
        acc[6]  += cA0.w * xx; acc[7]  += cA0.w * xy;
        acc[8]  += cA1.x * xx; acc[9]  += cA1.x * xy;
        acc[10] += cA1.y * xx; acc[11] += cA1.y * xy;
        acc[12] += cA1.z * xx; acc[13] += cA1.z * xy;
        acc[14] += cA1.w * xx; acc[15] += cA1.w * xy;
        rA = rB; rB = rC; rC = rD; x0 = x1; x1 = x2;
        cA0 = cB0; cA1 = cB1;
    }
}

// write one aggregated row into the swizzled LDS A-tile (row stride 2048 B)
__device__ __forceinline__ void write_lds_row(unsigned short* aT, int v, int lane,
                                              const float* acc) {
#pragma unroll
    for (int b = 0; b < 8; b++) {
        unsigned int o = (unsigned int)f2bf(acc[2 * b]) | ((unsigned int)f2bf(acc[2 * b + 1]) << 16);
        int chunk = b * 16 + (lane >> 2);
        int swc = chunk ^ (v & 15);
        *(unsigned int*)((char*)aT + (size_t)v * 2048 + swc * 16 + (lane & 3) * 4) = o;
    }
}

// ---- fused layer 0: aggregate 32 rows -> LDS -> GEMM @V1p -> ReLU -> hbf --
__global__ __launch_bounds__(512) void fused0_k(const int* __restrict__ offs,
                                                const int2* __restrict__ rec,
                                                const float* __restrict__ comp,
                                                const float* __restrict__ emb,
                                                const unsigned short* __restrict__ Bp,
                                                const float* __restrict__ bias,
                                                unsigned short* __restrict__ hbf) {
    __shared__ unsigned short aT[32 * 1024];   // 64 KB
    const int t = threadIdx.x;
    const int w = t >> 6, lane = t & 63;
    const int row0 = blockIdx.x * 32;
    float acc[16];
#pragma unroll
    for (int r = 0; r < 4; r++) {
        int v = w * 4 + r;
        agg_row<true>(offs, rec, comp, emb, nullptr, row0 + v, lane, acc);
        write_lds_row(aT, v, lane, acc);
    }
    __syncthreads();
    const int rl = lane & 15, g = lane >> 4;
    f32x4 c0 = (f32x4){0.f, 0.f, 0.f, 0.f};
    f32x4 c1 = (f32x4){0.f, 0.f, 0.f, 0.f};
#pragma unroll 4
    for (int kidx = 0; kidx < 32; kidx++) {
        bf16x8 bfr = *(const bf16x8*)(Bp + (((size_t)w * 32 + kidx) * 64 + lane) * 8);
        int ch = kidx * 4 + g;
        bf16x8 a0 = *(const bf16x8*)((const char*)aT + (size_t)rl * 2048 + (size_t)((ch ^ rl) * 16));
        bf16x8 a1 = *(const bf16x8*)((const char*)aT + (size_t)(rl + 16) * 2048 + (size_t)((ch ^ rl) * 16));
        c0 = __builtin_amdgcn_mfma_f32_16x16x32_bf16(a0, bfr, c0, 0, 0, 0);
        c1 = __builtin_amdgcn_mfma_f32_16x16x32_bf16(a1, bfr, c1, 0, 0, 0);
    }
    int col = w * 16 + rl;
    float bv = bias[col];
#pragma unroll
    for (int q = 0; q < 4; q++) {
        int r0 = row0 + g * 4 + q;
        float v0 = c0[q] + bv;
        float v1 = c1[q] + bv;
        v0 = v0 > 0.f ? v0 : 0.f;
        v1 = v1 > 0.f ? v1 : 0.f;
        hbf[(size_t)r0 * 128 + col] = f2bf(v0);
        hbf[(size_t)(r0 + 16) * 128 + col] = f2bf(v1);
    }
}

// ---- fused layer 1: aggregate 16 rows -> LDS -> K-split GEMM @V2p -> out --
__global__ __launch_bounds__(512) void fused1_k(const int* __restrict__ offs,
                                                const int2* __restrict__ rec,
                                                const float* __restrict__ comp,
                                                const unsigned short* __restrict__ hbf,
                                                const unsigned short* __restrict__ Bp,
                                                const float* __restrict__ bias,
                                                float* __restrict__ out) {
    __shared__ unsigned short aT[16 * 1024];   // 32 KB
    __shared__ f32x4 red[8 * 64];              // 8 KB partial C
    const int t = threadIdx.x;
    const int w = t >> 6, lane = t & 63;
    const int row0 = blockIdx.x * 16;
    float acc[16];
#pragma unroll
    for (int r = 0; r < 2; r++) {
        int v = w * 2 + r;
        agg_row<false>(offs, rec, comp, nullptr, hbf, row0 + v, lane, acc);
        write_lds_row(aT, v, lane, acc);
    }
    __syncthreads();
    const int kh = w >> 2, nt = w & 3;
    const int rl = lane & 15, g = lane >> 4;
    f32x4 c = (f32x4){0.f, 0.f, 0.f, 0.f};
#pragma unroll 4
    for (int k = 0; k < 16; k++) {
        int kidx = kh * 16 + k;
        bf16x8 bfr = *(const bf16x8*)(Bp + (((size_t)nt * 32 + kidx) * 64 + lane) * 8);
        int ch = kidx * 4 + g;
        bf16x8 a0 = *(const bf16x8*)((const char*)aT + (size_t)rl * 2048 + (size_t)((ch ^ rl) * 16));
        c = __builtin_amdgcn_mfma_f32_16x16x32_bf16(a0, bfr, c, 0, 0, 0);
    }
    red[w * 64 + lane] = c;
    __syncthreads();
    if (w < 4) {
        f32x4 a = red[w * 64 + lane];
        f32x4 b = red[(w + 4) * 64 + lane];
        int col = nt * 16 + rl;
        float bv = bias[col];
#pragma unroll
        for (int q = 0; q < 4; q++) {
            int r0 = row0 + g * 4 + q;
            out[(size_t)r0 * 64 + col] = a[q] + b[q] + bv;
        }
    }
}

extern "C" void kernel_launch(void* const* d_in, const int* in_sizes, int n_in,
                              void* d_out, int out_size, void* d_ws, size_t ws_size,
                              hipStream_t stream) {
    const int*   src_ids = (const int*)d_in[0];
    const int*   e0_src  = (const int*)d_in[1];
    const int*   e0_dst  = (const int*)d_in[2];
    const int*   e0_type = (const int*)d_in[3];
    const float* norm0   = (const float*)d_in[4];
    const int*   e1_src  = (const int*)d_in[5];
    const int*   e1_dst  = (const int*)d_in[6];
    const int*   e1_type = (const int*)d_in[7];
    const float* norm1   = (const float*)d_in[8];
    const float* emb     = (const float*)d_in[9];
    const float* V1      = (const float*)d_in[10];
    const float* comp1   = (const float*)d_in[11];
    const float* b1      = (const float*)d_in[12];
    const float* V2      = (const float*)d_in[13];
    const float* comp2   = (const float*)d_in[14];
    const float* b2      = (const float*)d_in[15];
    float* out = (float*)d_out;

    char* base = (char*)d_ws;
    size_t off = 0;
    auto alloc = [&](size_t bytes) -> char* {
        off = (off + 255) & ~(size_t)255;
        char* r = base + off;
        off += bytes;
        return r;
    };
    unsigned short* hbf = (unsigned short*)alloc((size_t)N1 * HD * 2);
    unsigned short* V1p = (unsigned short*)alloc((size_t)1024 * 128 * 2);
    unsigned short* V2p = (unsigned short*)alloc((size_t)1024 * 64 * 2);
    int*   deg    = (int*)alloc((size_t)(N1 + N2) * 4);
    int*   deg0   = deg;
    int*   deg1   = deg + N1;
    int*   offs0  = (int*)alloc((size_t)(N1 + 1) * 4);
    int*   cur0   = (int*)alloc((size_t)N1 * 4);
    int*   offs1  = (int*)alloc((size_t)(N2 + 1) * 4);
    int*   cur1   = (int*)alloc((size_t)N2 * 4);
    int2*  rec0   = (int2*)alloc((size_t)E0 * 8);
    int2*  rec1   = (int2*)alloc((size_t)E1 * 8);
    (void)ws_size; (void)in_sizes; (void)n_in; (void)out_size;

    hipMemsetAsync(deg, 0, (size_t)(N1 + N2) * 4, stream);

    setup_k<<<512, 256, 0, stream>>>(V1, V1p, V2, V2p, e0_dst, e1_dst, deg0, deg1);
    scan_k<<<2, 1024, 0, stream>>>(deg0, offs0, cur0, deg1, offs1, cur1);
    scatter_k<<<512, 256, 0, stream>>>(src_ids, e0_src, e0_dst, e0_type, norm0,
                                       cur0, rec0,
                                       e1_src, e1_dst, e1_type, norm1,
                                       cur1, rec1);
    fused0_k<<<N1 / 32, 512, 0, stream>>>(offs0, rec0, comp1, emb, V1p, b1, hbf);
    fused1_k<<<N2 / 16, 512, 0, stream>>>(offs1, rec1, comp2, hbf, V2p, b2, out);
}